// Round 12
// baseline (400.106 us; speedup 1.0000x reference)
//
#include <hip/hip_runtime.h>
#include <stdint.h>

// ---------------------------------------------------------------------------
// MLA attention, MI355X gfx950.
// Shapes: B=2 S=2048 D=2048 H=16 HD=128 ND=64 RD=64 R=512
// ABI: all 7 inputs fp32, output fp32. Internal: bf16 + fp32 accum.
//
// v15:
//   - attn = v13 base + FORCED-issue register-direct V (T14): 16x inline-asm
//     global_load_dwordx4 (saddr + 32b voffset) issued right after K dump
//     (asm volatile cannot be sunk -- v14's plain loads were sunk to use,
//     VGPR=104 proved it), consumed in PV behind s_waitcnt vmcnt(0) +
//     sched_barrier(0). Removes ~240 of ~600 DS cyc/wave-iter.
//   - fat projection moved gemm256 -> gemm128 (352 blocks: all 256 CUs busy
//     vs 176). gemm256 retained in source (un-instantiated) for revert.
// ---------------------------------------------------------------------------

typedef unsigned short u16;
typedef __bf16 bf16x8 __attribute__((ext_vector_type(8)));
typedef float f32x4 __attribute__((ext_vector_type(4)));
typedef int i32x4 __attribute__((ext_vector_type(4)));

#define QLD 2816   // qcat row stride (padded for 256-col GEMM tiles)

__device__ __forceinline__ float bf2f(u16 u) {
    union { unsigned int i; float f; } x; x.i = ((unsigned int)u) << 16; return x.f;
}
__device__ __forceinline__ u16 f2bf(float f) {
    union { float f; unsigned int i; } x; x.f = f;
    unsigned int r = x.i + 0x7fffu + ((x.i >> 16) & 1u);   // RNE, finite inputs only
    return (u16)(r >> 16);
}
__device__ __forceinline__ void store_c(u16* p, float v)  { *p = f2bf(v); }
__device__ __forceinline__ void store_c(float* p, float v){ *p = v; }

#define GLOBAL_AS __attribute__((address_space(1)))
#define LDS_AS    __attribute__((address_space(3)))
__device__ __forceinline__ void gl_lds16(const void* g, void* l) {
    __builtin_amdgcn_global_load_lds((GLOBAL_AS const void*)g, (LDS_AS void*)l, 16, 0, 0);
}

#if __has_builtin(__builtin_amdgcn_exp2f)
__device__ __forceinline__ float exp2fast(float x) { return __builtin_amdgcn_exp2f(x); }
#else
__device__ __forceinline__ float exp2fast(float x) { return __expf(x * 0.6931471805599453f); }
#endif

// 16-lane (DPP row) max reduce on the VALU pipe.
template<int CTRL>
__device__ __forceinline__ float fmax_dpp(float v) {
    int s = __builtin_bit_cast(int, v);
    int t = __builtin_amdgcn_update_dpp(s, s, CTRL, 0xF, 0xF, true);
    return fmaxf(v, __builtin_bit_cast(float, t));
}
__device__ __forceinline__ float rowmax16(float v) {
    v = fmax_dpp<0xB1>(v);    // QUAD_PERM [1,0,3,2]  (xor 1)
    v = fmax_dpp<0x4E>(v);    // QUAD_PERM [2,3,0,1]  (xor 2)
    v = fmax_dpp<0x124>(v);   // ROW_ROR:4
    v = fmax_dpp<0x128>(v);   // ROW_ROR:8
    return v;
}

// convert 8 fp32 -> 8 bf16 at chunk index i
__device__ __forceinline__ void cv8(const float* __restrict__ src,
                                    u16* __restrict__ dst, int i) {
    const float4* s = (const float4*)src;
    float4 v0 = s[2*i], v1 = s[2*i + 1];
    union { u16 u[8]; uint4 v; } o;
    o.u[0] = f2bf(v0.x); o.u[1] = f2bf(v0.y); o.u[2] = f2bf(v0.z); o.u[3] = f2bf(v0.w);
    o.u[4] = f2bf(v1.x); o.u[5] = f2bf(v1.y); o.u[6] = f2bf(v1.z); o.u[7] = f2bf(v1.w);
    *((uint4*)(dst + 8*i)) = o.v;
}

// ---------------------------------------------------------------------------
// Fused input conversion: 6 segments, all sizes multiples of 256 chunks so
// every block is segment-uniform. (total 1,916,928 chunks -> grid 7488)
// ---------------------------------------------------------------------------
__global__ void convert_all(const float* __restrict__ s_x,
                            const float* __restrict__ s_wq,
                            const float* __restrict__ s_kvd,
                            const float* __restrict__ s_kup,
                            const float* __restrict__ s_vup,
                            const float* __restrict__ s_kr,
                            u16* __restrict__ xc, u16* __restrict__ wqcat,
                            u16* __restrict__ kupc, u16* __restrict__ vupc) {
    int i = blockIdx.x * 256 + threadIdx.x;
    if      (i < 1048576) cv8(s_x,   xc,                          i);
    else if (i < 1572864) cv8(s_wq,  wqcat,                       i - 1048576);
    else if (i < 1703936) cv8(s_kvd, wqcat + (size_t)2112*2048,   i - 1572864);
    else if (i < 1769472) cv8(s_kup, kupc,                        i - 1703936);
    else if (i < 1900544) cv8(s_vup, vupc,                        i - 1769472);
    else if (i < 1916928) cv8(s_kr,  wqcat + (size_t)2048*2048,   i - 1900544);
}

// ---------------------------------------------------------------------------
// GEMM 256x256, deep pipeline (v8). Currently un-instantiated (fat moved to
// gemm128); kept for easy revert.
// ---------------------------------------------------------------------------
template<typename CT>
__global__ __launch_bounds__(512, 2)
void gemm256(const u16* __restrict__ A, const u16* __restrict__ W,
             CT* __restrict__ C, int K, int lda, int ldw, int ldc) {
    __shared__ u16 lds[4][16384];   // 4 x 32 KB (A: [0,8192), B: [8192,16384))
    const int tid  = threadIdx.x;
    const int lane = tid & 63, l15 = lane & 15, quad = lane >> 4;
    const int wave = tid >> 6;
    const int wr = wave >> 2, wc = wave & 3;
    const int bm = blockIdx.y * 256;
    const int bn = blockIdx.x * 256;

    const int R = tid >> 2, slot = tid & 3;
    const int k16 = slot ^ ((R >> 1) & 3);
    const u16* asrc = A + (size_t)(bm + R) * lda + k16 * 8;
    const u16* bsrc = W + (size_t)(bn + R) * ldw + k16 * 8;
    const size_t astep = (size_t)128 * lda;
    const size_t bstep = (size_t)128 * ldw;

    #define STAGE256(st, bi) { \
        const u16* a0_ = asrc + (size_t)(st) * 32; \
        const u16* b0_ = bsrc + (size_t)(st) * 32; \
        gl_lds16(a0_,         &lds[bi][tid * 8]); \
        gl_lds16(a0_ + astep, &lds[bi][(tid + 512) * 8]); \
        gl_lds16(b0_,         &lds[bi][(tid + 1024) * 8]); \
        gl_lds16(b0_ + bstep, &lds[bi][(tid + 1536) * 8]); \
    }

    const f32x4 fzero = {0.f, 0.f, 0.f, 0.f};
    f32x4 acc[8][4];
    #pragma unroll
    for (int i = 0; i < 8; ++i)
        #pragma unroll
        for (int j = 0; j < 4; ++j) acc[i][j] = fzero;

    const int aswz = (quad ^ ((l15 >> 1) & 3)) * 8;

    const int nst = K >> 5;
    STAGE256(0, 0)
    STAGE256(1, 1)
    STAGE256(2, 2)
    asm volatile("s_waitcnt vmcnt(8)" ::: "memory");
    __builtin_amdgcn_s_barrier();

    for (int t = 0; t < nst; ++t) {
        const u16* buf = lds[t & 3];
        bf16x8 af[8], bfv[4];
        #pragma unroll
        for (int mf = 0; mf < 8; ++mf)
            af[mf] = *reinterpret_cast<const bf16x8*>(
                &buf[(wr*128 + mf*16 + l15)*32 + aswz]);
        #pragma unroll
        for (int nf = 0; nf < 4; ++nf)
            bfv[nf] = *reinterpret_cast<const bf16x8*>(
                &buf[8192 + (wc*64 + nf*16 + l15)*32 + aswz]);
        int st = t + 3; if (st > nst - 1) st = nst - 1;
        STAGE256(st, (t + 3) & 3)
        __builtin_amdgcn_s_setprio(1);
        #pragma unroll
        for (int mf = 0; mf < 8; ++mf)
            #pragma unroll
            for (int nf = 0; nf < 4; ++nf)
                acc[mf][nf] = __builtin_amdgcn_mfma_f32_16x16x32_bf16(
                    af[mf], bfv[nf], acc[mf][nf], 0, 0, 0);
        __builtin_amdgcn_s_setprio(0);
        asm volatile("s_waitcnt vmcnt(8) lgkmcnt(0)" ::: "memory");
        __builtin_amdgcn_sched_barrier(0);
        __builtin_amdgcn_s_barrier();
        __builtin_amdgcn_sched_barrier(0);
    }
    #undef STAGE256

    #pragma unroll
    for (int mf = 0; mf < 8; ++mf)
        #pragma unroll
        for (int nf = 0; nf < 4; ++nf)
            #pragma unroll
            for (int r = 0; r < 4; ++r) {
                int gm = bm + wr*128 + mf*16 + quad*4 + r;
                int gn = bn + wc*64 + nf*16 + l15;
                store_c(&C[(size_t)gm * ldc + gn], acc[mf][nf][r]);
            }
}

// ---------------------------------------------------------------------------
// GEMM 128x256 deep-pipeline BODY (3-buffer rotation, LDS passed in so
// multiple call sites share one allocation). 512 threads = 8 waves (2Mx4N).
// EPI: 0 = C[gm*ldc+gn]; 1 = k_eff column remap gn -> (gn>>6)*128+(gn&63).
// ---------------------------------------------------------------------------
template<int EPI, typename CT>
__device__ __forceinline__ void gemm128_body(
        u16 (*lds)[12288],
        const u16* __restrict__ A, const u16* __restrict__ W,
        CT* __restrict__ C, int K, int lda, int ldw, int ldc,
        int bm, int bn) {
    const int tid  = threadIdx.x;
    const int lane = tid & 63, l15 = lane & 15, quad = lane >> 4;
    const int wave = tid >> 6;
    const int wr = wave >> 2, wc = wave & 3;

    const int R = tid >> 2, slot = tid & 3;
    const int k16 = slot ^ ((R >> 1) & 3);
    const u16* asrc = A + (size_t)(bm + R) * lda + k16 * 8;   // R < 128
    const u16* bsrc = W + (size_t)(bn + R) * ldw + k16 * 8;
    const size_t bstep = (size_t)128 * ldw;

    #define STAGE128(st, bi) { \
        const u16* a0_ = asrc + (size_t)(st) * 32; \
        const u16* b0_ = bsrc + (size_t)(st) * 32; \
        gl_lds16(a0_,         &lds[bi][tid * 8]); \
        gl_lds16(b0_,         &lds[bi][(tid + 512) * 8]); \
        gl_lds16(b0_ + bstep, &lds[bi][(tid + 1024) * 8]); \
    }

    const f32x4 fzero = {0.f, 0.f, 0.f, 0.f};
    f32x4 acc[4][4];
    #pragma unroll
    for (int i = 0; i < 4; ++i)
        #pragma unroll
        for (int j = 0; j < 4; ++j) acc[i][j] = fzero;

    const int aswz = (quad ^ ((l15 >> 1) & 3)) * 8;

    const int nst = K >> 5;
    STAGE128(0, 0)
    STAGE128(1, 1)
    asm volatile("s_waitcnt vmcnt(3)" ::: "memory");
    __builtin_amdgcn_s_barrier();

    int b0 = 0, bs = 2;   // current read buffer; stage target (t+2)%3
    for (int t = 0; t < nst; ++t) {
        const u16* buf = lds[b0];
        bf16x8 af[4], bfv[4];
        #pragma unroll
        for (int mf = 0; mf < 4; ++mf)
            af[mf] = *reinterpret_cast<const bf16x8*>(
                &buf[(wr*64 + mf*16 + l15)*32 + aswz]);
        #pragma unroll
        for (int nf = 0; nf < 4; ++nf)
            bfv[nf] = *reinterpret_cast<const bf16x8*>(
                &buf[4096 + (wc*64 + nf*16 + l15)*32 + aswz]);
        int st = t + 2; if (st > nst - 1) st = nst - 1;
        STAGE128(st, bs)
        __builtin_amdgcn_s_setprio(1);
        #pragma unroll
        for (int mf = 0; mf < 4; ++mf)
            #pragma unroll
            for (int nf = 0; nf < 4; ++nf)
                acc[mf][nf] = __builtin_amdgcn_mfma_f32_16x16x32_bf16(
                    af[mf], bfv[nf], acc[mf][nf], 0, 0, 0);
        __builtin_amdgcn_s_setprio(0);
        asm volatile("s_waitcnt vmcnt(3) lgkmcnt(0)" ::: "memory");
        __builtin_amdgcn_sched_barrier(0);
        __builtin_amdgcn_s_barrier();
        __builtin_amdgcn_sched_barrier(0);
        b0 = (b0 == 2) ? 0 : b0 + 1;
        bs = (bs == 2) ? 0 : bs + 1;
    }
    #undef STAGE128

    #pragma unroll
    for (int mf = 0; mf < 4; ++mf)
        #pragma unroll
        for (int nf = 0; nf < 4; ++nf)
            #pragma unroll
            for (int r = 0; r < 4; ++r) {
                int gm = bm + wr*64 + mf*16 + quad*4 + r;
                int gn = bn + wc*64 + nf*16 + l15;
                size_t ci;
                if (EPI == 1) ci = (size_t)gm*ldc + ((gn >> 6)*128 + (gn & 63));
                else          ci = (size_t)gm*ldc + gn;
                store_c(&C[ci], acc[mf][nf][r]);
            }
}

// standalone 128x256 GEMM (fat projection, out-proj)
template<typename CT>
__global__ __launch_bounds__(512, 4)
void gemm128(const u16* __restrict__ A, const u16* __restrict__ W,
             CT* __restrict__ C, int K, int lda, int ldw, int ldc) {
    __shared__ u16 lds[3][12288];
    gemm128_body<0>(lds, A, W, C, K, lda, ldw, ldc,
                    (int)blockIdx.y * 128, (int)blockIdx.x * 256);
}

// ---------------------------------------------------------------------------
// Fused k_up + v_up: 384 blocks x 512 threads, concurrent block ranges.
// ---------------------------------------------------------------------------
__global__ __launch_bounds__(512, 4)
void kv_up(const u16* __restrict__ ckv, const u16* __restrict__ kupc,
           u16* __restrict__ keff, const u16* __restrict__ vupc,
           u16* __restrict__ vT) {
    __shared__ u16 lds[3][12288];
    const int bx = blockIdx.x;
    if (bx < 128) {
        // k_up: grid (4 N-tiles, 32 M-tiles)
        int bn = (bx & 3) * 256, bm = (bx >> 2) * 128;
        gemm128_body<1>(lds, ckv, kupc, keff, 512, QLD, 512, 2048, bm, bn);
    } else {
        // v_up: grid (16 N-tiles, 16 M-tiles)
        int b2 = bx - 128;
        int bn = (b2 & 15) * 256, bm = (b2 >> 4) * 128;
        gemm128_body<0>(lds, vupc, ckv, vT, 512, 512, QLD, 4096, bm, bn);
    }
}

// ---------------------------------------------------------------------------
// Fused post-fat kernel: blocks 0..511 do RoPE (q in-place + k_rope rotate
// and broadcast into k_eff); blocks 512..2559 convert wo fp32->bf16.
// ---------------------------------------------------------------------------
__global__ void rope_woc(u16* __restrict__ qcat, u16* __restrict__ keff,
                         const float* __restrict__ wo_src, u16* __restrict__ woc) {
    const int blk = blockIdx.x;
    if (blk >= 512) {
        int i = (blk - 512) * 256 + threadIdx.x;   // 0..524287
        cv8(wo_src, woc, i);
        return;
    }
    int idx = blk * 256 + threadIdx.x;   // 131,072 total
    int i = idx & 31, r = idx >> 5;
    int pos = r & 2047;
    float freq = powf(10000.0f, -(float)i * (1.0f/32.0f));
    float ang  = (float)pos * freq;
    float s = sinf(ang), c = cosf(ang);

    // (a) q rotate, 16 heads
    u16* row = qcat + (size_t)r * QLD + 64 + 2*i;
    #pragma unroll
    for (int h = 0; h < 16; ++h) {
        unsigned int* p = (unsigned int*)(row + h*128);
        unsigned int v = *p;
        float x0 = bf2f((u16)(v & 0xffffu)), x1 = bf2f((u16)(v >> 16));
        unsigned int lo = f2bf(x0*c - x1*s);
        unsigned int hi = f2bf(x1*c + x0*s);
        *p = lo | (hi << 16);
    }

    // (b) k_rope rotate + broadcast into keff
    const u16* p = qcat + (size_t)r * QLD + 2048 + 2*i;
    float x0 = bf2f(p[0]), x1 = bf2f(p[1]);
    union { u16 u[2]; unsigned int w; } o;
    o.u[0] = f2bf(x0*c - x1*s);
    o.u[1] = f2bf(x1*c + x0*s);
    unsigned int* base = (unsigned int*)(keff + (size_t)r*2048 + 64 + 2*i);
    #pragma unroll
    for (int h = 0; h < 16; ++h) base[h*64] = o.w;   // 128 u16 = 64 u32 stride
}

// ---------------------------------------------------------------------------
// Flash-style causal attention, v15: K LDS-staged (proven v13), V register-
// direct with FORCED early issue (inline-asm global_load_dwordx4, cannot be
// sunk by the scheduler), consumed behind vmcnt(0)+sched_barrier before PV.
// grid = (16, 32) = 512 blocks; XCD-local bh groups; paired q-tiles.
// ---------------------------------------------------------------------------
__global__ __launch_bounds__(256, 2)
void attn_kernel(u16* __restrict__ qcat, const u16* __restrict__ KE,
                 const u16* __restrict__ VT) {
    constexpr int S = 2048;
    const int L = (int)blockIdx.y * 16 + (int)blockIdx.x;
    const int xcd = L & 7, j = L >> 3;
    const int bh   = xcd * 4 + (j & 3);   // 4 heads per XCD
    const int pair = j >> 2;              // 0..15
    const int b = bh >> 4, h = bh & 15;

    __shared__ u16 Ks[64*128];     // K tile, chunk-swizzled by (row&15), 16 KB
    __shared__ u16 Ps[64*68];      // P, row stride 68, 8.7 KB

    const int tid  = threadIdx.x;
    const int lane = tid & 63, l15 = lane & 15, quad = lane >> 4;
    const int wave = tid >> 6;

    // K staging sources (swizzle folded into global address)
    const u16* ksrc[4];
    #pragma unroll
    for (int i = 0; i < 4; ++i) {
        int g = tid + i*256;
        int r = g >> 4, slot = g & 15, cg = slot ^ (r & 15);
        ksrc[i] = KE + (size_t)(b*S + r)*2048 + h*128 + cg*8;
    }

    // V byte-offset base for saddr-form loads: row h*128+l15, col b*S+quad*8
    const unsigned vbase0 = (unsigned)((((h*128 + l15) * 4096) + b*S + quad*8) * 2);

    // prefetch K tile 0 (of the first half)
    bf16x8 kreg[4];
    #pragma unroll
    for (int i = 0; i < 4; ++i)
        kreg[i] = *reinterpret_cast<const bf16x8*>(ksrc[i]);

    // all-ones bf16 B-frag for MFMA row-sums
    union { u16 u[8]; bf16x8 v; } onesu;
    #pragma unroll
    for (int i = 0; i < 8; ++i) onesu.u[i] = 0x3f80;
    const bf16x8 ones = onesu.v;

    const f32x4 fzero = {0.f, 0.f, 0.f, 0.f};
    const float NEG = -1e30f;
    const float KLOG = 0.12751739f;     // (1/sqrt(128)) * log2(e)
    const float THR = 8.0f;             // defer-rescale threshold (exp2 domain)

    __bf16* PsB = reinterpret_cast<__bf16*>(Ps);

    for (int half = 0; half < 2; ++half) {
        const int qt = half ? pair : 31 - pair;
        const int nkt = qt + 1;

        // Q A-frags in registers: A[m=l15][k=quad*8+j], 4 k-steps of 32
        u16* qbase = qcat + (size_t)(b*S + qt*64) * QLD + h*128;
        bf16x8 aq[4];
        #pragma unroll
        for (int ks = 0; ks < 4; ++ks)
            aq[ks] = *reinterpret_cast<const bf16x8*>(
                qbase + (size_t)(wave*16 + l15)*QLD + ks*32 + quad*8);

        float m2[4]  = {NEG, NEG, NEG, NEG};   // running max, exp2 domain
        float l_i[4] = {0.f, 0.f, 0.f, 0.f};
        f32x4 oacc[8];
        #pragma unroll
        for (int i = 0; i < 8; ++i) oacc[i] = fzero;

        const int qrow0 = qt*64 + wave*16 + quad*4;

        for (int kt = 0; kt < nkt; ++kt) {
            const bool is_last = (kt == nkt - 1);
            // dump prefetched K tile kt to LDS (vector writes, linear layout)
            #pragma unroll
            for (int i = 0; i < 4; ++i)
                *reinterpret_cast<bf16x8*>(&Ks[(tid + i*256) * 8]) = kreg[i];

            // FORCED-issue V loads for THIS tile (asm volatile: not sinkable).
            // Per instr: 16 rows x 64B contiguous from vT; consumed in PV
            // ~900 cyc later (QK + softmax cover).
            i32x4 vraw[2][8];
            {
                const unsigned bkt = vbase0 + (unsigned)(kt * 128);
                #pragma unroll
                for (int ks = 0; ks < 2; ++ks)
                    #pragma unroll
                    for (int ntv = 0; ntv < 8; ++ntv) {
                        unsigned voff = bkt + (unsigned)(ntv*131072 + ks*64);
                        asm volatile("global_load_dwordx4 %0, %1, %2"
                                     : "=v"(vraw[ks][ntv])
                                     : "v"(voff), "s"(VT));
                    }
            }

            // prefetch next K tile; wraps to tile 0 = second half's first
            {
                int ktn = (kt + 1 < nkt) ? kt + 1 : 0;
                #pragma unroll
                for (int i = 0; i < 4; ++i)
                    kreg[i] = *reinterpret_cast<const bf16x8*>(ksrc[i] + (size_t)ktn*(64*2048));
            }
            __syncthreads();

            // S = Q K^T (16 q-rows x 64 kv-cols per wave), RAW (no scale)
            f32x4 sfr[4];
            __builtin_amdgcn_s_setprio(1);
            #pragma unroll
            for (int nt = 0; nt < 4; ++nt) {
                f32x4 s = fzero;
                int n = nt*16 + l15;
                #pragma unroll
                for (int ks = 0; ks < 4; ++ks) {
                    int c = ks*4 + quad;
                    bf16x8 bk = *reinterpret_cast<const bf16x8*>(&Ks[n*128 + ((c ^ l15) * 8)]);
                    s = __builtin_amdgcn_mfma_f32_16x16x32_bf16(aq[ks], bk, s, 0, 0, 0);
                }
                sfr[nt] = s;
            }
            __builtin_amdgcn_s_setprio(0);
            // causal mask: only the diagonal tile needs it
            if (is_last) {
                #pragma unroll
                for (int nt = 0; nt < 4; ++nt) {
                    int kg = kt*64 + nt*16 + l15;
                    #pragma unroll
                    for (int r = 0; r < 4; ++r)
                        if (kg > qrow0 + r) sfr[nt][r] = NEG;
                }
            }
            // raw-domain row max via DPP
            float rm[4];
            #pragma unroll
            for (int r = 0; r < 4; ++r) {
                rm[r] = fmaxf(fmaxf(sfr[0][r], sfr[1][r]), fmaxf(sfr[2][r], sfr[3][r]));
                rm[r] = rowmax16(rm[r]);
            }
            // defer-rescale: only pay alpha when max grows by > THR (exp2 dom)
            float c2[4];
            int need = 0;
            #pragma unroll
            for (int r = 0; r < 4; ++r) {
                c2[r] = rm[r] * KLOG;
                need |= (c2[r] > m2[r] + THR) ? 1 : 0;
            }
            if (__any(need)) {
                float alpha[4];
                #pragma unroll
                for (int r = 0; r < 4; ++r) {
                    float mn = fmaxf(m2[r], c2[r]);
                    alpha[r] = exp2fast(m2[r] - mn);
                    m2[r] = mn;
                    l_i[r] *= alpha[r];
                }
                #pragma unroll
                for (int i = 0; i < 8; ++i)
                    #pragma unroll
                    for (int r = 0; r < 4; ++r)
                        oacc[i][r] *= alpha[r];
            }
            // P = exp2(S*KLOG - m2): one FMA + one exp per element
            float pf[4][4];
            #pragma unroll
            for (int nt = 0; nt < 4; ++nt)
                #pragma unroll
                for (int r = 0; r < 4; ++r)
                    pf[nt][r] = exp2fast(__builtin_fmaf(sfr[nt][r], KLOG, -m2[r]));

            // P -> LDS via compiler scalar __bf16 casts (m240: no hand asm)
            #pragma unroll
            for (int nt = 0; nt < 4; ++nt) {
                int base = (wave*16 + quad*4)*68 + nt*16 + l15;
                #pragma unroll
                for (int r = 0; r < 4; ++r)
                    PsB[base + r*68] = (__bf16)pf[nt][r];
            }

            // drain the V loads, pin ordering (rule #18), then PV from regs
            asm volatile("s_waitcnt vmcnt(0)" ::: "memory");
            __builtin_amdgcn_sched_barrier(0);
            f32x4 lfr = fzero;
            __builtin_amdgcn_s_setprio(1);
            #pragma unroll
            for (int ks = 0; ks < 2; ++ks) {
                bf16x8 pa = *reinterpret_cast<const bf16x8*>(
                    &Ps[(wave*16 + l15)*68 + ks*32 + quad*8]);
                lfr = __builtin_amdgcn_mfma_f32_16x16x32_bf16(pa, ones, lfr, 0, 0, 0);
                #pragma unroll
                for (int ntv = 0; ntv < 8; ++ntv)
                    oacc[ntv] = __builtin_amdgcn_mfma_f32_16x16x32_bf16(
                        pa, __builtin_bit_cast(bf16x8, vraw[ks][ntv]), oacc[ntv], 0, 0, 0);
            }
            __builtin_amdgcn_s_setprio(0);
            #pragma unroll
            for (int r = 0; r < 4; ++r) l_i[r] += lfr[r];
            __syncthreads();
        }

        // epilogue: normalize, write IN PLACE over this half's own Q rows
        #pragma unroll
        for (int r = 0; r < 4; ++r) {
            float inv = 1.0f / l_i[r];
            int qrow = wave*16 + quad*4 + r;
            #pragma unroll
            for (int ntv = 0; ntv < 8; ++ntv) {
                int d = ntv*16 + l15;
                qbase[(size_t)qrow*QLD + d] = f2bf(oacc[ntv][r] * inv);
            }
        }
    }
}

// ---------------------------------------------------------------------------
// Host launcher. Inputs fp32, output fp32. 6 dispatches total.
// ---------------------------------------------------------------------------
extern "C" void kernel_launch(void* const* d_in, const int* in_sizes, int n_in,
                              void* d_out, int out_size, void* d_ws, size_t ws_size,
                              hipStream_t stream) {
    (void)in_sizes; (void)n_in; (void)out_size; (void)ws_size;
    float* out = (float*)d_out;
    char* ws = (char*)d_ws;

    // workspace (bytes), total 71,303,168 (< proven 77.3 MB)
    u16* xc     = (u16*)(ws);                  // 4096x2048   16,777,216  (vT reuses)
    u16* qcat   = (u16*)(ws + 16777216);       // 4096x2816   23,068,672
    u16* keff   = (u16*)(ws + 39845888);       // 4096x2048   16,777,216
    u16* wqcat  = (u16*)(ws + 56623104);       // 2816x2048   11,534,336  (rows 2688+ garbage -> unread pad cols; woc reuses)
    u16* kupc   = (u16*)(ws + 68157440);       // 1024x512     1,048,576
    u16* vupc   = (u16*)(ws + 69206016);       // 2048x512     2,097,152
    u16* vT     = xc;      // xc dead after projection GEMM
    u16* woc    = wqcat;   // wqcat dead after projection GEMM

    // 1) fused fp32 -> bf16 conversion of the 6 pre-GEMM inputs
    convert_all<<<7488, 256, 0, stream>>>(
        (const float*)d_in[0], (const float*)d_in[1], (const float*)d_in[2],
        (const float*)d_in[3], (const float*)d_in[5], (const float*)d_in[4],
        xc, wqcat, kupc, vupc);

    // 2) fat projection: qcat = xc @ wqcat^T (N=2816 incl. pad cols)
    //    gemm128: 352 blocks -> all 256 CUs busy (was 176 with gemm256).
    gemm128<u16><<<dim3(11, 32), 512, 0, stream>>>(
        xc, wqcat, qcat, 2048, 2048, 2048, QLD);

    // 3) fused RoPE (q in-place, k_rope -> k_eff) + wo convert into dead wqcat
    rope_woc<<<2560, 256, 0, stream>>>(qcat, keff, (const float*)d_in[6], woc);

    // 4) fused k_up + v_up (concurrent block ranges)
    kv_up<<<384, 512, 0, stream>>>(qcat + 2112, kupc, keff, vupc, vT);

    // 5) attention (XCD-local pairs, K LDS-staged, V forced register-direct)
    attn_kernel<<<dim3(16, 32), 256, 0, stream>>>(qcat, keff, vT);

    // 6) output projection -> fp32 d_out
    gemm128<float><<<dim3(8, 32), 512, 0, stream>>>(
        qcat, woc, out, 2048, QLD, 2048, 2048);
}

// Round 13
// 306.866 us; speedup vs baseline: 1.3038x; 1.3038x over previous
//
#include <hip/hip_runtime.h>
#include <stdint.h>

// ---------------------------------------------------------------------------
// MLA attention, MI355X gfx950.
// Shapes: B=2 S=2048 D=2048 H=16 HD=128 ND=64 RD=64 R=512
// ABI: all 7 inputs fp32, output fp32. Internal: bf16 + fp32 accum.
//
// v16 = v13 (310.5 us proven) + attn single-barrier double-buffered K/V:
//   - Ks[2]/Vs[2]; dump tile t into buf[t&1]; ONE __syncthreads per iter
//     (barrier-ordering proof: overwrite of buf[t%2] at iter t+2 happens
//     after BARRIER(t+1), which follows all iter-t reads). Removes 33
//     barrier drains + lets waves phase-drift (QK || softmax overlap).
//   - Ps is wave-private (no barrier needed). Cross-half barrier added.
//   - register-direct V abandoned (v12/v14/v15: allocator defeats it).
//   - fat projection back on gemm256 (v13 config).
// ---------------------------------------------------------------------------

typedef unsigned short u16;
typedef __bf16 bf16x8 __attribute__((ext_vector_type(8)));
typedef float f32x4 __attribute__((ext_vector_type(4)));

#define QLD 2816   // qcat row stride (padded for 256-col GEMM tiles)

__device__ __forceinline__ float bf2f(u16 u) {
    union { unsigned int i; float f; } x; x.i = ((unsigned int)u) << 16; return x.f;
}
__device__ __forceinline__ u16 f2bf(float f) {
    union { float f; unsigned int i; } x; x.f = f;
    unsigned int r = x.i + 0x7fffu + ((x.i >> 16) & 1u);   // RNE, finite inputs only
    return (u16)(r >> 16);
}
__device__ __forceinline__ void store_c(u16* p, float v)  { *p = f2bf(v); }
__device__ __forceinline__ void store_c(float* p, float v){ *p = v; }

#define GLOBAL_AS __attribute__((address_space(1)))
#define LDS_AS    __attribute__((address_space(3)))
__device__ __forceinline__ void gl_lds16(const void* g, void* l) {
    __builtin_amdgcn_global_load_lds((GLOBAL_AS const void*)g, (LDS_AS void*)l, 16, 0, 0);
}

#if __has_builtin(__builtin_amdgcn_exp2f)
__device__ __forceinline__ float exp2fast(float x) { return __builtin_amdgcn_exp2f(x); }
#else
__device__ __forceinline__ float exp2fast(float x) { return __expf(x * 0.6931471805599453f); }
#endif

// 16-lane (DPP row) max reduce on the VALU pipe.
template<int CTRL>
__device__ __forceinline__ float fmax_dpp(float v) {
    int s = __builtin_bit_cast(int, v);
    int t = __builtin_amdgcn_update_dpp(s, s, CTRL, 0xF, 0xF, true);
    return fmaxf(v, __builtin_bit_cast(float, t));
}
__device__ __forceinline__ float rowmax16(float v) {
    v = fmax_dpp<0xB1>(v);    // QUAD_PERM [1,0,3,2]  (xor 1)
    v = fmax_dpp<0x4E>(v);    // QUAD_PERM [2,3,0,1]  (xor 2)
    v = fmax_dpp<0x124>(v);   // ROW_ROR:4
    v = fmax_dpp<0x128>(v);   // ROW_ROR:8
    return v;
}

// convert 8 fp32 -> 8 bf16 at chunk index i
__device__ __forceinline__ void cv8(const float* __restrict__ src,
                                    u16* __restrict__ dst, int i) {
    const float4* s = (const float4*)src;
    float4 v0 = s[2*i], v1 = s[2*i + 1];
    union { u16 u[8]; uint4 v; } o;
    o.u[0] = f2bf(v0.x); o.u[1] = f2bf(v0.y); o.u[2] = f2bf(v0.z); o.u[3] = f2bf(v0.w);
    o.u[4] = f2bf(v1.x); o.u[5] = f2bf(v1.y); o.u[6] = f2bf(v1.z); o.u[7] = f2bf(v1.w);
    *((uint4*)(dst + 8*i)) = o.v;
}

// ---------------------------------------------------------------------------
// Fused input conversion: 6 segments, all sizes multiples of 256 chunks so
// every block is segment-uniform. (total 1,916,928 chunks -> grid 7488)
// ---------------------------------------------------------------------------
__global__ void convert_all(const float* __restrict__ s_x,
                            const float* __restrict__ s_wq,
                            const float* __restrict__ s_kvd,
                            const float* __restrict__ s_kup,
                            const float* __restrict__ s_vup,
                            const float* __restrict__ s_kr,
                            u16* __restrict__ xc, u16* __restrict__ wqcat,
                            u16* __restrict__ kupc, u16* __restrict__ vupc) {
    int i = blockIdx.x * 256 + threadIdx.x;
    if      (i < 1048576) cv8(s_x,   xc,                          i);
    else if (i < 1572864) cv8(s_wq,  wqcat,                       i - 1048576);
    else if (i < 1703936) cv8(s_kvd, wqcat + (size_t)2112*2048,   i - 1572864);
    else if (i < 1769472) cv8(s_kup, kupc,                        i - 1703936);
    else if (i < 1900544) cv8(s_vup, vupc,                        i - 1769472);
    else if (i < 1916928) cv8(s_kr,  wqcat + (size_t)2048*2048,   i - 1900544);
}

// ---------------------------------------------------------------------------
// GEMM 256x256, deep pipeline (v8): fat projection.
// ---------------------------------------------------------------------------
template<typename CT>
__global__ __launch_bounds__(512, 2)
void gemm256(const u16* __restrict__ A, const u16* __restrict__ W,
             CT* __restrict__ C, int K, int lda, int ldw, int ldc) {
    __shared__ u16 lds[4][16384];   // 4 x 32 KB (A: [0,8192), B: [8192,16384))
    const int tid  = threadIdx.x;
    const int lane = tid & 63, l15 = lane & 15, quad = lane >> 4;
    const int wave = tid >> 6;
    const int wr = wave >> 2, wc = wave & 3;
    const int bm = blockIdx.y * 256;
    const int bn = blockIdx.x * 256;

    const int R = tid >> 2, slot = tid & 3;
    const int k16 = slot ^ ((R >> 1) & 3);
    const u16* asrc = A + (size_t)(bm + R) * lda + k16 * 8;
    const u16* bsrc = W + (size_t)(bn + R) * ldw + k16 * 8;
    const size_t astep = (size_t)128 * lda;
    const size_t bstep = (size_t)128 * ldw;

    #define STAGE256(st, bi) { \
        const u16* a0_ = asrc + (size_t)(st) * 32; \
        const u16* b0_ = bsrc + (size_t)(st) * 32; \
        gl_lds16(a0_,         &lds[bi][tid * 8]); \
        gl_lds16(a0_ + astep, &lds[bi][(tid + 512) * 8]); \
        gl_lds16(b0_,         &lds[bi][(tid + 1024) * 8]); \
        gl_lds16(b0_ + bstep, &lds[bi][(tid + 1536) * 8]); \
    }

    const f32x4 fzero = {0.f, 0.f, 0.f, 0.f};
    f32x4 acc[8][4];
    #pragma unroll
    for (int i = 0; i < 8; ++i)
        #pragma unroll
        for (int j = 0; j < 4; ++j) acc[i][j] = fzero;

    const int aswz = (quad ^ ((l15 >> 1) & 3)) * 8;

    const int nst = K >> 5;
    STAGE256(0, 0)
    STAGE256(1, 1)
    STAGE256(2, 2)
    asm volatile("s_waitcnt vmcnt(8)" ::: "memory");
    __builtin_amdgcn_s_barrier();

    for (int t = 0; t < nst; ++t) {
        const u16* buf = lds[t & 3];
        bf16x8 af[8], bfv[4];
        #pragma unroll
        for (int mf = 0; mf < 8; ++mf)
            af[mf] = *reinterpret_cast<const bf16x8*>(
                &buf[(wr*128 + mf*16 + l15)*32 + aswz]);
        #pragma unroll
        for (int nf = 0; nf < 4; ++nf)
            bfv[nf] = *reinterpret_cast<const bf16x8*>(
                &buf[8192 + (wc*64 + nf*16 + l15)*32 + aswz]);
        int st = t + 3; if (st > nst - 1) st = nst - 1;
        STAGE256(st, (t + 3) & 3)
        __builtin_amdgcn_s_setprio(1);
        #pragma unroll
        for (int mf = 0; mf < 8; ++mf)
            #pragma unroll
            for (int nf = 0; nf < 4; ++nf)
                acc[mf][nf] = __builtin_amdgcn_mfma_f32_16x16x32_bf16(
                    af[mf], bfv[nf], acc[mf][nf], 0, 0, 0);
        __builtin_amdgcn_s_setprio(0);
        asm volatile("s_waitcnt vmcnt(8) lgkmcnt(0)" ::: "memory");
        __builtin_amdgcn_sched_barrier(0);
        __builtin_amdgcn_s_barrier();
        __builtin_amdgcn_sched_barrier(0);
    }
    #undef STAGE256

    #pragma unroll
    for (int mf = 0; mf < 8; ++mf)
        #pragma unroll
        for (int nf = 0; nf < 4; ++nf)
            #pragma unroll
            for (int r = 0; r < 4; ++r) {
                int gm = bm + wr*128 + mf*16 + quad*4 + r;
                int gn = bn + wc*64 + nf*16 + l15;
                store_c(&C[(size_t)gm * ldc + gn], acc[mf][nf][r]);
            }
}

// ---------------------------------------------------------------------------
// GEMM 128x256 deep-pipeline BODY (3-buffer rotation, LDS passed in so
// multiple call sites share one allocation). 512 threads = 8 waves (2Mx4N).
// EPI: 0 = C[gm*ldc+gn]; 1 = k_eff column remap gn -> (gn>>6)*128+(gn&63).
// ---------------------------------------------------------------------------
template<int EPI, typename CT>
__device__ __forceinline__ void gemm128_body(
        u16 (*lds)[12288],
        const u16* __restrict__ A, const u16* __restrict__ W,
        CT* __restrict__ C, int K, int lda, int ldw, int ldc,
        int bm, int bn) {
    const int tid  = threadIdx.x;
    const int lane = tid & 63, l15 = lane & 15, quad = lane >> 4;
    const int wave = tid >> 6;
    const int wr = wave >> 2, wc = wave & 3;

    const int R = tid >> 2, slot = tid & 3;
    const int k16 = slot ^ ((R >> 1) & 3);
    const u16* asrc = A + (size_t)(bm + R) * lda + k16 * 8;   // R < 128
    const u16* bsrc = W + (size_t)(bn + R) * ldw + k16 * 8;
    const size_t bstep = (size_t)128 * ldw;

    #define STAGE128(st, bi) { \
        const u16* a0_ = asrc + (size_t)(st) * 32; \
        const u16* b0_ = bsrc + (size_t)(st) * 32; \
        gl_lds16(a0_,         &lds[bi][tid * 8]); \
        gl_lds16(b0_,         &lds[bi][(tid + 512) * 8]); \
        gl_lds16(b0_ + bstep, &lds[bi][(tid + 1024) * 8]); \
    }

    const f32x4 fzero = {0.f, 0.f, 0.f, 0.f};
    f32x4 acc[4][4];
    #pragma unroll
    for (int i = 0; i < 4; ++i)
        #pragma unroll
        for (int j = 0; j < 4; ++j) acc[i][j] = fzero;

    const int aswz = (quad ^ ((l15 >> 1) & 3)) * 8;

    const int nst = K >> 5;
    STAGE128(0, 0)
    STAGE128(1, 1)
    asm volatile("s_waitcnt vmcnt(3)" ::: "memory");
    __builtin_amdgcn_s_barrier();

    int b0 = 0, bs = 2;   // current read buffer; stage target (t+2)%3
    for (int t = 0; t < nst; ++t) {
        const u16* buf = lds[b0];
        bf16x8 af[4], bfv[4];
        #pragma unroll
        for (int mf = 0; mf < 4; ++mf)
            af[mf] = *reinterpret_cast<const bf16x8*>(
                &buf[(wr*64 + mf*16 + l15)*32 + aswz]);
        #pragma unroll
        for (int nf = 0; nf < 4; ++nf)
            bfv[nf] = *reinterpret_cast<const bf16x8*>(
                &buf[4096 + (wc*64 + nf*16 + l15)*32 + aswz]);
        int st = t + 2; if (st > nst - 1) st = nst - 1;
        STAGE128(st, bs)
        __builtin_amdgcn_s_setprio(1);
        #pragma unroll
        for (int mf = 0; mf < 4; ++mf)
            #pragma unroll
            for (int nf = 0; nf < 4; ++nf)
                acc[mf][nf] = __builtin_amdgcn_mfma_f32_16x16x32_bf16(
                    af[mf], bfv[nf], acc[mf][nf], 0, 0, 0);
        __builtin_amdgcn_s_setprio(0);
        asm volatile("s_waitcnt vmcnt(3) lgkmcnt(0)" ::: "memory");
        __builtin_amdgcn_sched_barrier(0);
        __builtin_amdgcn_s_barrier();
        __builtin_amdgcn_sched_barrier(0);
        b0 = (b0 == 2) ? 0 : b0 + 1;
        bs = (bs == 2) ? 0 : bs + 1;
    }
    #undef STAGE128

    #pragma unroll
    for (int mf = 0; mf < 4; ++mf)
        #pragma unroll
        for (int nf = 0; nf < 4; ++nf)
            #pragma unroll
            for (int r = 0; r < 4; ++r) {
                int gm = bm + wr*64 + mf*16 + quad*4 + r;
                int gn = bn + wc*64 + nf*16 + l15;
                size_t ci;
                if (EPI == 1) ci = (size_t)gm*ldc + ((gn >> 6)*128 + (gn & 63));
                else          ci = (size_t)gm*ldc + gn;
                store_c(&C[ci], acc[mf][nf][r]);
            }
}

// standalone 128x256 GEMM (out-proj)
template<typename CT>
__global__ __launch_bounds__(512, 4)
void gemm128(const u16* __restrict__ A, const u16* __restrict__ W,
             CT* __restrict__ C, int K, int lda, int ldw, int ldc) {
    __shared__ u16 lds[3][12288];
    gemm128_body<0>(lds, A, W, C, K, lda, ldw, ldc,
                    (int)blockIdx.y * 128, (int)blockIdx.x * 256);
}

// ---------------------------------------------------------------------------
// Fused k_up + v_up: 384 blocks x 512 threads, concurrent block ranges.
// ---------------------------------------------------------------------------
__global__ __launch_bounds__(512, 4)
void kv_up(const u16* __restrict__ ckv, const u16* __restrict__ kupc,
           u16* __restrict__ keff, const u16* __restrict__ vupc,
           u16* __restrict__ vT) {
    __shared__ u16 lds[3][12288];
    const int bx = blockIdx.x;
    if (bx < 128) {
        // k_up: grid (4 N-tiles, 32 M-tiles)
        int bn = (bx & 3) * 256, bm = (bx >> 2) * 128;
        gemm128_body<1>(lds, ckv, kupc, keff, 512, QLD, 512, 2048, bm, bn);
    } else {
        // v_up: grid (16 N-tiles, 16 M-tiles)
        int b2 = bx - 128;
        int bn = (b2 & 15) * 256, bm = (b2 >> 4) * 128;
        gemm128_body<0>(lds, vupc, ckv, vT, 512, 512, QLD, 4096, bm, bn);
    }
}

// ---------------------------------------------------------------------------
// Fused post-fat kernel: blocks 0..511 do RoPE (q in-place + k_rope rotate
// and broadcast into k_eff); blocks 512..2559 convert wo fp32->bf16.
// ---------------------------------------------------------------------------
__global__ void rope_woc(u16* __restrict__ qcat, u16* __restrict__ keff,
                         const float* __restrict__ wo_src, u16* __restrict__ woc) {
    const int blk = blockIdx.x;
    if (blk >= 512) {
        int i = (blk - 512) * 256 + threadIdx.x;   // 0..524287
        cv8(wo_src, woc, i);
        return;
    }
    int idx = blk * 256 + threadIdx.x;   // 131,072 total
    int i = idx & 31, r = idx >> 5;
    int pos = r & 2047;
    float freq = powf(10000.0f, -(float)i * (1.0f/32.0f));
    float ang  = (float)pos * freq;
    float s = sinf(ang), c = cosf(ang);

    // (a) q rotate, 16 heads
    u16* row = qcat + (size_t)r * QLD + 64 + 2*i;
    #pragma unroll
    for (int h = 0; h < 16; ++h) {
        unsigned int* p = (unsigned int*)(row + h*128);
        unsigned int v = *p;
        float x0 = bf2f((u16)(v & 0xffffu)), x1 = bf2f((u16)(v >> 16));
        unsigned int lo = f2bf(x0*c - x1*s);
        unsigned int hi = f2bf(x1*c + x0*s);
        *p = lo | (hi << 16);
    }

    // (b) k_rope rotate + broadcast into keff
    const u16* p = qcat + (size_t)r * QLD + 2048 + 2*i;
    float x0 = bf2f(p[0]), x1 = bf2f(p[1]);
    union { u16 u[2]; unsigned int w; } o;
    o.u[0] = f2bf(x0*c - x1*s);
    o.u[1] = f2bf(x1*c + x0*s);
    unsigned int* base = (unsigned int*)(keff + (size_t)r*2048 + 64 + 2*i);
    #pragma unroll
    for (int h = 0; h < 16; ++h) base[h*64] = o.w;   // 128 u16 = 64 u32 stride
}

// ---------------------------------------------------------------------------
// Flash-style causal attention, v16: double-buffered K/V LDS tiles, ONE
// barrier per KV iteration. grid = (16, 32) = 512 blocks, 4 waves each;
// XCD-local bh groups; paired q-tiles (33 iters/block uniform).
// Safety: dump(buf[t&1]); BARRIER(t); reads(buf[t&1]). Overwrite of
// buf[t&1] happens at iter t+2, after BARRIER(t+1) > all iter-t reads.
// Cross-half barrier after epilogue. Ps is wave-private (no hazard).
// ---------------------------------------------------------------------------
__global__ __launch_bounds__(256, 2)
void attn_kernel(u16* __restrict__ qcat, const u16* __restrict__ KE,
                 const u16* __restrict__ VT) {
    constexpr int S = 2048;
    const int L = (int)blockIdx.y * 16 + (int)blockIdx.x;
    const int xcd = L & 7, j = L >> 3;
    const int bh   = xcd * 4 + (j & 3);   // 4 heads per XCD
    const int pair = j >> 2;              // 0..15
    const int b = bh >> 4, h = bh & 15;

    __shared__ u16 Ks[2][64*128];  // K tiles, chunk-swizzled by (row&15), 32 KB
    __shared__ u16 Vs[2][128*64];  // V^T tiles, chunk-swizzled by (d&7), 32 KB
    __shared__ u16 Ps[64*68];      // P, row stride 68, wave-private rows, 8.7 KB

    const int tid  = threadIdx.x;
    const int lane = tid & 63, l15 = lane & 15, quad = lane >> 4;
    const int wave = tid >> 6;

    // staging sources (swizzle folded into global address)
    const u16* ksrc[4];
    const u16* vsrc[4];
    #pragma unroll
    for (int i = 0; i < 4; ++i) {
        int g = tid + i*256;
        { // K: 64 rows x 256B; chunk slot (g&15) holds logical chunk slot^(row&15)
            int r = g >> 4, slot = g & 15, cg = slot ^ (r & 15);
            ksrc[i] = KE + (size_t)(b*S + r)*2048 + h*128 + cg*8;
        }
        { // V: 128 rows x 128B; chunk slot (g&7) holds logical chunk slot^(d&7)
            int d = g >> 3, slot = g & 7, cg = slot ^ (d & 7);
            vsrc[i] = VT + (size_t)(h*128 + d)*4096 + (size_t)(b*S) + cg*8;
        }
    }

    // prefetch tile 0 (of the first half)
    bf16x8 kreg[4], vreg[4];
    #pragma unroll
    for (int i = 0; i < 4; ++i) {
        kreg[i] = *reinterpret_cast<const bf16x8*>(ksrc[i]);
        vreg[i] = *reinterpret_cast<const bf16x8*>(vsrc[i]);
    }

    // all-ones bf16 B-frag for MFMA row-sums
    union { u16 u[8]; bf16x8 v; } onesu;
    #pragma unroll
    for (int i = 0; i < 8; ++i) onesu.u[i] = 0x3f80;
    const bf16x8 ones = onesu.v;

    const f32x4 fzero = {0.f, 0.f, 0.f, 0.f};
    const float NEG = -1e30f;
    const float KLOG = 0.12751739f;     // (1/sqrt(128)) * log2(e)
    const float THR = 8.0f;             // defer-rescale threshold (exp2 domain)

    __bf16* PsB = reinterpret_cast<__bf16*>(Ps);

    for (int half = 0; half < 2; ++half) {
        const int qt = half ? pair : 31 - pair;
        const int nkt = qt + 1;

        // Q A-frags in registers: A[m=l15][k=quad*8+j], 4 k-steps of 32
        u16* qbase = qcat + (size_t)(b*S + qt*64) * QLD + h*128;
        bf16x8 aq[4];
        #pragma unroll
        for (int ks = 0; ks < 4; ++ks)
            aq[ks] = *reinterpret_cast<const bf16x8*>(
                qbase + (size_t)(wave*16 + l15)*QLD + ks*32 + quad*8);

        float m2[4]  = {NEG, NEG, NEG, NEG};   // running max, exp2 domain
        float l_i[4] = {0.f, 0.f, 0.f, 0.f};
        f32x4 oacc[8];
        #pragma unroll
        for (int i = 0; i < 8; ++i) oacc[i] = fzero;

        const int qrow0 = qt*64 + wave*16 + quad*4;

        for (int kt = 0; kt < nkt; ++kt) {
            const bool is_last = (kt == nkt - 1);
            const int pb = kt & 1;
            // dump prefetched tile kt into buffer pb (vector writes, linear)
            #pragma unroll
            for (int i = 0; i < 4; ++i) {
                *reinterpret_cast<bf16x8*>(&Ks[pb][(tid + i*256) * 8]) = kreg[i];
                *reinterpret_cast<bf16x8*>(&Vs[pb][(tid + i*256) * 8]) = vreg[i];
            }
            // prefetch next tile; wraps to tile 0 = second half's first tile
            {
                int ktn = (kt + 1 < nkt) ? kt + 1 : 0;
                #pragma unroll
                for (int i = 0; i < 4; ++i) {
                    kreg[i] = *reinterpret_cast<const bf16x8*>(ksrc[i] + (size_t)ktn*(64*2048));
                    vreg[i] = *reinterpret_cast<const bf16x8*>(vsrc[i] + (size_t)ktn*64);
                }
            }
            __syncthreads();   // the ONLY barrier this iteration

            // S = Q K^T (16 q-rows x 64 kv-cols per wave), RAW (no scale)
            f32x4 sfr[4];
            __builtin_amdgcn_s_setprio(1);
            #pragma unroll
            for (int nt = 0; nt < 4; ++nt) {
                f32x4 s = fzero;
                int n = nt*16 + l15;
                #pragma unroll
                for (int ks = 0; ks < 4; ++ks) {
                    int c = ks*4 + quad;
                    bf16x8 bk = *reinterpret_cast<const bf16x8*>(&Ks[pb][n*128 + ((c ^ l15) * 8)]);
                    s = __builtin_amdgcn_mfma_f32_16x16x32_bf16(aq[ks], bk, s, 0, 0, 0);
                }
                sfr[nt] = s;
            }
            __builtin_amdgcn_s_setprio(0);
            // causal mask: only the diagonal tile needs it
            if (is_last) {
                #pragma unroll
                for (int nt = 0; nt < 4; ++nt) {
                    int kg = kt*64 + nt*16 + l15;
                    #pragma unroll
                    for (int r = 0; r < 4; ++r)
                        if (kg > qrow0 + r) sfr[nt][r] = NEG;
                }
            }
            // raw-domain row max via DPP
            float rm[4];
            #pragma unroll
            for (int r = 0; r < 4; ++r) {
                rm[r] = fmaxf(fmaxf(sfr[0][r], sfr[1][r]), fmaxf(sfr[2][r], sfr[3][r]));
                rm[r] = rowmax16(rm[r]);
            }
            // defer-rescale: only pay alpha when max grows by > THR (exp2 dom)
            float c2[4];
            int need = 0;
            #pragma unroll
            for (int r = 0; r < 4; ++r) {
                c2[r] = rm[r] * KLOG;
                need |= (c2[r] > m2[r] + THR) ? 1 : 0;
            }
            if (__any(need)) {
                float alpha[4];
                #pragma unroll
                for (int r = 0; r < 4; ++r) {
                    float mn = fmaxf(m2[r], c2[r]);
                    alpha[r] = exp2fast(m2[r] - mn);
                    m2[r] = mn;
                    l_i[r] *= alpha[r];
                }
                #pragma unroll
                for (int i = 0; i < 8; ++i)
                    #pragma unroll
                    for (int r = 0; r < 4; ++r)
                        oacc[i][r] *= alpha[r];
            }
            // P = exp2(S*KLOG - m2): one FMA + one exp per element
            float pf[4][4];
            #pragma unroll
            for (int nt = 0; nt < 4; ++nt)
                #pragma unroll
                for (int r = 0; r < 4; ++r)
                    pf[nt][r] = exp2fast(__builtin_fmaf(sfr[nt][r], KLOG, -m2[r]));

            // P -> LDS (wave-private rows; no barrier needed)
            #pragma unroll
            for (int nt = 0; nt < 4; ++nt) {
                int base = (wave*16 + quad*4)*68 + nt*16 + l15;
                #pragma unroll
                for (int r = 0; r < 4; ++r)
                    PsB[base + r*68] = (__bf16)pf[nt][r];
            }

            // O += P V, and row-sums l += P·1 via ones-MFMA on the same pa frags
            f32x4 lfr = fzero;
            __builtin_amdgcn_s_setprio(1);
            #pragma unroll
            for (int ks = 0; ks < 2; ++ks) {
                bf16x8 pa = *reinterpret_cast<const bf16x8*>(
                    &Ps[(wave*16 + l15)*68 + ks*32 + quad*8]);
                lfr = __builtin_amdgcn_mfma_f32_16x16x32_bf16(pa, ones, lfr, 0, 0, 0);
                #pragma unroll
                for (int ntv = 0; ntv < 8; ++ntv) {
                    int c = ks*4 + quad;
                    bf16x8 bv = *reinterpret_cast<const bf16x8*>(
                        &Vs[pb][(ntv*16 + l15)*64 + ((c ^ (l15 & 7)) * 8)]);
                    oacc[ntv] = __builtin_amdgcn_mfma_f32_16x16x32_bf16(pa, bv, oacc[ntv], 0, 0, 0);
                }
            }
            __builtin_amdgcn_s_setprio(0);
            #pragma unroll
            for (int r = 0; r < 4; ++r) l_i[r] += lfr[r];
            // no trailing barrier: next iter writes buf[pb^1] (disjoint)
        }

        // epilogue: normalize, write IN PLACE over this half's own Q rows
        #pragma unroll
        for (int r = 0; r < 4; ++r) {
            float inv = 1.0f / l_i[r];
            int qrow = wave*16 + quad*4 + r;
            #pragma unroll
            for (int ntv = 0; ntv < 8; ++ntv) {
                int d = ntv*16 + l15;
                qbase[(size_t)qrow*QLD + d] = f2bf(oacc[ntv][r] * inv);
            }
        }
        // cross-half fence: half 1 iter 0 dumps buf[0], which slow waves
        // may still be reading from half 0's last iteration.
        __syncthreads();
    }
}

// ---------------------------------------------------------------------------
// Host launcher. Inputs fp32, output fp32. 6 dispatches total.
// ---------------------------------------------------------------------------
extern "C" void kernel_launch(void* const* d_in, const int* in_sizes, int n_in,
                              void* d_out, int out_size, void* d_ws, size_t ws_size,
                              hipStream_t stream) {
    (void)in_sizes; (void)n_in; (void)out_size; (void)ws_size;
    float* out = (float*)d_out;
    char* ws = (char*)d_ws;

    // workspace (bytes), total 71,303,168 (< proven 77.3 MB)
    u16* xc     = (u16*)(ws);                  // 4096x2048   16,777,216  (vT reuses)
    u16* qcat   = (u16*)(ws + 16777216);       // 4096x2816   23,068,672
    u16* keff   = (u16*)(ws + 39845888);       // 4096x2048   16,777,216
    u16* wqcat  = (u16*)(ws + 56623104);       // 2816x2048   11,534,336  (rows 2688+ garbage -> unread pad cols; woc reuses)
    u16* kupc   = (u16*)(ws + 68157440);       // 1024x512     1,048,576
    u16* vupc   = (u16*)(ws + 69206016);       // 2048x512     2,097,152
    u16* vT     = xc;      // xc dead after projection GEMM
    u16* woc    = wqcat;   // wqcat dead after projection GEMM

    // 1) fused fp32 -> bf16 conversion of the 6 pre-GEMM inputs
    convert_all<<<7488, 256, 0, stream>>>(
        (const float*)d_in[0], (const float*)d_in[1], (const float*)d_in[2],
        (const float*)d_in[3], (const float*)d_in[5], (const float*)d_in[4],
        xc, wqcat, kupc, vupc);

    // 2) fat projection: qcat = xc @ wqcat^T   (N=2816 incl. pad cols)
    gemm256<u16><<<dim3(11, 16), 512, 0, stream>>>(
        xc, wqcat, qcat, 2048, 2048, 2048, QLD);

    // 3) fused RoPE (q in-place, k_rope -> k_eff) + wo convert into dead wqcat
    rope_woc<<<2560, 256, 0, stream>>>(qcat, keff, (const float*)d_in[6], woc);

    // 4) fused k_up + v_up (concurrent block ranges)
    kv_up<<<384, 512, 0, stream>>>(qcat + 2112, kupc, keff, vupc, vT);

    // 5) attention (XCD-local pairs, double-buffered K/V, 1 barrier/iter)
    attn_kernel<<<dim3(16, 32), 256, 0, stream>>>(qcat, keff, vT);

    // 6) output projection -> fp32 d_out
    gemm128<float><<<dim3(8, 32), 512, 0, stream>>>(
        qcat, woc, out, 2048, QLD, 2048, 2048);
}